// Round 3
// baseline (1665.787 us; speedup 1.0000x reference)
//
#include <hip/hip_runtime.h>

// LSA fused attention: out = softmax(QK^T/temp, diag=-inf) @ V
// B=64, N=1024, D=768, fp32 I/O, bf16 MFMA 32x32x16.
//
// Pipeline: 3 prepass kernels rewrite Q(scaled),K,V as MFMA-fragment-ordered
// bf16 images in d_ws; main kernel stages 16KB frag blocks via
// global_load_lds (coalesced, zero staging VALU), ds_read b128 at
// base+lane*16 (conflict-free), swapped-operand MFMA, online softmax with
// lane-local q, fragment-layout P, LDS-transposed coalesced epilogue.
//
// Frag images (32x32x16 bf16):
//  Q: per (b,qt): blk[(step*4+ks)*2+mr][lane][16B], lane l -> q=mr*32+(l&31),
//     k=step*64+ks*16+8*(l>>5)+j
//  K: per (b,t,step): blk[ks*4+nc][lane][16B], kv=nc*32+(l&31), k same
//  V: per (b,t,jg*2+kh): blk[ks*4+nc][lane][16B], d=jg*128+nc*32+(l&31),
//     kv=kh*64+ks*16+8*(l>>5)+j   (transposed)

typedef __bf16 bf16x8 __attribute__((ext_vector_type(8)));
typedef __bf16 bf16x4 __attribute__((ext_vector_type(4)));
typedef float  f32x16 __attribute__((ext_vector_type(16)));
typedef float  f32x4v __attribute__((ext_vector_type(4)));

#define WS_Q 0UL
#define WS_K 100663296UL
#define WS_V 201326592UL
#define WS_NEEDED 301989888UL

// main-kernel LDS map
#define QOFF   0          // 96 KB: 96 frag blocks
#define KVOFF  98304      // 2 x 16 KB double buffer (reused as O-transpose 32KB)
#define POFF   131072     // 16 KB: P frag blocks [(mr*2+kh)*4+ks]
#define REDOFF 147456     // 1 KB reduce buffer
#define LDS_MAIN 148480

__device__ __forceinline__ void gld16(const void* g, const char* l) {
    __builtin_amdgcn_global_load_lds(
        (const __attribute__((address_space(1))) unsigned int*)g,
        (__attribute__((address_space(3))) unsigned int*)(l), 16, 0, 0);
}

// ============================ prepass: Q ============================
__global__ __launch_bounds__(256) void prep_q(const float* __restrict__ Qg,
                                              const float* __restrict__ Tg,
                                              unsigned short* __restrict__ Qws) {
    __shared__ __align__(16) unsigned short L[64 * 72];   // stride 144B
    const int bid = blockIdx.x;            // b*16 + qt
    const int tid = threadIdx.x;
    const float scale2 = 1.4426950408889634f / Tg[0];     // log2(e)/temp
    const float* src = Qg + (size_t)bid * 64 * 768;
    char* outb = (char*)Qws + (size_t)bid * 98304;
    const int q  = tid >> 2;
    const int k0 = (tid & 3) * 16;
    #pragma unroll 1
    for (int st = 0; st < 12; ++st) {
        #pragma unroll
        for (int i = 0; i < 4; ++i) {
            f32x4v v = *(const f32x4v*)(src + (size_t)q * 768 + st * 64 + k0 + i * 4);
            bf16x4 hb = { (__bf16)(v[0] * scale2), (__bf16)(v[1] * scale2),
                          (__bf16)(v[2] * scale2), (__bf16)(v[3] * scale2) };
            *(bf16x4*)((char*)L + q * 144 + (k0 + i * 4) * 2) = hb;
        }
        __syncthreads();
        #pragma unroll
        for (int i = 0; i < 2; ++i) {
            int u = tid * 2 + i;                       // [0,512)
            int ks = u >> 7, mrr = (u >> 6) & 1, l = u & 63;
            bf16x8 f = *(const bf16x8*)((char*)L + (mrr * 32 + (l & 31)) * 144
                                        + ks * 32 + 16 * (l >> 5));
            *(bf16x8*)(outb + (size_t)st * 8192 + u * 16) = f;
        }
        __syncthreads();
    }
}

// ============================ prepass: K ============================
__global__ __launch_bounds__(512) void prep_k(const float* __restrict__ Kg,
                                              unsigned short* __restrict__ Kws) {
    __shared__ __align__(16) unsigned short L[128 * 72];  // stride 144B
    const int bid = blockIdx.x;            // b*8 + t
    const int tid = threadIdx.x;
    const float* src = Kg + (size_t)bid * 128 * 768;
    char* outb = (char*)Kws + (size_t)bid * 196608;
    const int kv = tid >> 2;
    const int k0 = (tid & 3) * 16;
    #pragma unroll 1
    for (int st = 0; st < 12; ++st) {
        #pragma unroll
        for (int i = 0; i < 4; ++i) {
            f32x4v v = *(const f32x4v*)(src + (size_t)kv * 768 + st * 64 + k0 + i * 4);
            bf16x4 hb = { (__bf16)v[0], (__bf16)v[1], (__bf16)v[2], (__bf16)v[3] };
            *(bf16x4*)((char*)L + kv * 144 + (k0 + i * 4) * 2) = hb;
        }
        __syncthreads();
        #pragma unroll
        for (int i = 0; i < 2; ++i) {
            int u = tid * 2 + i;                       // [0,1024)
            int ks = u >> 8, ncc = (u >> 6) & 3, l = u & 63;
            bf16x8 f = *(const bf16x8*)((char*)L + (ncc * 32 + (l & 31)) * 144
                                        + ks * 32 + 16 * (l >> 5));
            *(bf16x8*)(outb + (size_t)st * 16384 + u * 16) = f;
        }
        __syncthreads();
    }
}

// ============================ prepass: V (transpose) ============================
__global__ __launch_bounds__(512) void prep_v(const float* __restrict__ Vg,
                                              unsigned short* __restrict__ Vws) {
    __shared__ __align__(16) unsigned short L[128 * 136]; // V^T [d 128][kv], stride 272B
    const int bid = blockIdx.x;            // b*8 + t
    const int tid = threadIdx.x;
    const float* src = Vg + (size_t)bid * 128 * 768;
    char* outb = (char*)Vws + (size_t)bid * 196608;
    const int srg = tid & 31, scg = tid >> 5;
    #pragma unroll 1
    for (int jg = 0; jg < 6; ++jg) {
        #pragma unroll
        for (int i2 = 0; i2 < 2; ++i2) {
            int cg = scg + i2 * 16;
            const float* vp = src + (size_t)(srg * 4) * 768 + jg * 128 + cg * 4;
            f32x4v a0 = *(const f32x4v*)(vp);
            f32x4v a1 = *(const f32x4v*)(vp + 768);
            f32x4v a2 = *(const f32x4v*)(vp + 1536);
            f32x4v a3 = *(const f32x4v*)(vp + 2304);
            #pragma unroll
            for (int c = 0; c < 4; ++c) {
                int d = cg * 4 + c;
                bf16x4 hb = { (__bf16)a0[c], (__bf16)a1[c], (__bf16)a2[c], (__bf16)a3[c] };
                *(bf16x4*)((char*)L + d * 272 + srg * 8) = hb;
            }
        }
        __syncthreads();
        #pragma unroll
        for (int i = 0; i < 4; ++i) {
            int u = tid * 4 + i;                       // [0,2048)
            int kh = u >> 10, ks = (u >> 8) & 3, ncc = (u >> 6) & 3, l = u & 63;
            bf16x8 f = *(const bf16x8*)((char*)L + (ncc * 32 + (l & 31)) * 272
                                        + kh * 128 + ks * 32 + 16 * (l >> 5));
            *(bf16x8*)(outb + (size_t)(jg * 2 + kh) * 16384 + (u & 1023) * 16) = f;
        }
        __syncthreads();
    }
}

// ============================ main kernel ============================
__global__ __launch_bounds__(512) void lsa_main(
    const unsigned short* __restrict__ Qws, const unsigned short* __restrict__ Kws,
    const unsigned short* __restrict__ Vws, float* __restrict__ Og)
{
    extern __shared__ char sm[];
    const int tid  = threadIdx.x;
    const int lane = tid & 63;
    const int w    = tid >> 6;
    const int mr   = w & 1;
    const int nc   = w >> 1;
    const int hh   = lane >> 5;
    const int l31  = lane & 31;

    int id = blockIdx.x;
    int xcd = id & 7, jj = id >> 3;
    int batch = (jj >> 5) * 16 + xcd * 2 + ((jj >> 4) & 1);
    int qt = jj & 15;

    const char* qimg = (const char*)Qws + (size_t)(batch * 16 + qt) * 98304;
    const char* kimg = (const char*)Kws + (size_t)batch * 1572864;
    const char* vimg = (const char*)Vws + (size_t)batch * 1572864;
    float* redb = (float*)(sm + REDOFF);

    #define STAGE16(gsrc, loff) do {                                  \
        gld16((gsrc) + tid * 16,        sm + (loff) + w * 1024);      \
        gld16((gsrc) + 8192 + tid * 16, sm + (loff) + 8192 + w * 1024); } while (0)

    // prologue: stage Q image (96KB) + K(t=0, step=0)
    #pragma unroll
    for (int i = 0; i < 12; ++i)
        gld16(qimg + i * 8192 + tid * 16, sm + QOFF + i * 8192 + w * 1024);
    STAGE16(kimg, KVOFF);
    __syncthreads();

    f32x16 acc[6];
    #pragma unroll
    for (int jg = 0; jg < 6; ++jg)
        #pragma unroll
        for (int r = 0; r < 16; ++r) acc[jg][r] = 0.0f;
    float m_st = -1e30f, l_st = 0.0f;

    const int qglob = qt * 64 + mr * 32 + l31;
    const int diag_tile = qt >> 1;

    #pragma unroll 1
    for (int t = 0; t < 8; ++t) {
        const char* kt = kimg + (size_t)t * 196608;
        const char* vt = vimg + (size_t)t * 196608;

        // ---------------- QK^T: 12 steps, dbuf ----------------
        f32x16 s;
        #pragma unroll
        for (int r = 0; r < 16; ++r) s[r] = 0.0f;

        #pragma unroll
        for (int st = 0; st < 12; ++st) {
            const int cur = KVOFF + (st & 1) * 16384;
            if (st < 11) STAGE16(kt + (st + 1) * 16384, KVOFF + ((st + 1) & 1) * 16384);
            else         STAGE16(vt, KVOFF);           // V(jg0,kh0) -> buf0
            #pragma unroll
            for (int ks = 0; ks < 4; ++ks) {
                bf16x8 qf = *(const bf16x8*)(sm + QOFF + ((st * 4 + ks) * 2 + mr) * 1024 + lane * 16);
                bf16x8 kf = *(const bf16x8*)(sm + cur + (ks * 4 + nc) * 1024 + lane * 16);
                s = __builtin_amdgcn_mfma_f32_32x32x16_bf16(kf, qf, s, 0, 0, 0);
            }
            __syncthreads();
        }

        // diagonal self-exclusion
        if (t == diag_tile) {
            #pragma unroll
            for (int r = 0; r < 16; ++r) {
                int kvg = t * 128 + nc * 32 + (r & 3) + 8 * (r >> 2) + 4 * hh;
                if (kvg == qglob) s[r] = -1e30f;
            }
        }

        // ---------------- online softmax (lane-local q) ----------------
        float pm = s[0];
        #pragma unroll
        for (int r = 1; r < 16; ++r) pm = fmaxf(pm, s[r]);
        pm = fmaxf(pm, __shfl_xor(pm, 32, 64));
        if (hh == 0) redb[(mr * 32 + l31) * 4 + nc] = pm;
        __syncthreads();
        f32x4v m4 = *(const f32x4v*)(redb + (mr * 32 + l31) * 4);
        float mnew = fmaxf(fmaxf(m4[0], m4[1]), fmaxf(m4[2], m4[3]));
        mnew = fmaxf(mnew, m_st);
        float cf = __builtin_amdgcn_exp2f(m_st - mnew);
        m_st = mnew;

        float pl = 0.0f;
        #pragma unroll
        for (int r = 0; r < 16; ++r) {
            float e = __builtin_amdgcn_exp2f(s[r] - mnew);
            s[r] = e; pl += e;
        }
        pl += __shfl_xor(pl, 32, 64);
        l_st = l_st * cf + pl;

        #pragma unroll
        for (int jg = 0; jg < 6; ++jg)
            #pragma unroll
            for (int r = 0; r < 16; ++r) acc[jg][r] *= cf;

        // P -> fragment layout (8B chunks)
        #pragma unroll
        for (int g = 0; g < 4; ++g) {
            int kv0 = nc * 32 + 8 * g + 4 * hh;
            int kh = kv0 >> 6, r6 = kv0 & 63;
            int ks = r6 >> 4, hp = (r6 >> 3) & 1, j0 = r6 & 7;
            bf16x4 p4 = { (__bf16)s[4 * g + 0], (__bf16)s[4 * g + 1],
                          (__bf16)s[4 * g + 2], (__bf16)s[4 * g + 3] };
            *(bf16x4*)(sm + POFF + ((mr * 2 + kh) * 4 + ks) * 1024
                       + (hp * 32 + l31) * 16 + j0 * 2) = p4;
        }
        __syncthreads();

        // P frags for this q-group (held across all PV steps)
        bf16x8 pa[8];
        #pragma unroll
        for (int kh = 0; kh < 2; ++kh)
            #pragma unroll
            for (int ks = 0; ks < 4; ++ks)
                pa[kh * 4 + ks] = *(const bf16x8*)(sm + POFF + ((mr * 2 + kh) * 4 + ks) * 1024 + lane * 16);

        // ---------------- P @ V: 12 steps, dbuf ----------------
        #pragma unroll
        for (int p = 0; p < 12; ++p) {
            const int cur = KVOFF + (p & 1) * 16384;
            if (p < 11)      STAGE16(vt + (p + 1) * 16384, KVOFF + ((p + 1) & 1) * 16384);
            else if (t < 7)  STAGE16(kt + 196608, KVOFF);  // K(t+1, step0) -> buf0
            const int jg = p >> 1, kh = p & 1;
            #pragma unroll
            for (int ks = 0; ks < 4; ++ks) {
                bf16x8 vf = *(const bf16x8*)(sm + cur + (ks * 4 + nc) * 1024 + lane * 16);
                acc[jg] = __builtin_amdgcn_mfma_f32_32x32x16_bf16(vf, pa[kh * 4 + ks], acc[jg], 0, 0, 0);
            }
            __syncthreads();
        }
    }

    // ---------------- epilogue ----------------
    if (hh == 0) redb[(mr * 32 + l31) * 4 + nc] = l_st;
    __syncthreads();
    f32x4v l4 = *(const f32x4v*)(redb + (mr * 32 + l31) * 4);
    float rinv = 1.0f / (l4[0] + l4[1] + l4[2] + l4[3]);

    float* ob = Og + ((size_t)batch * 1024 + qt * 64) * 768;
    char* obl = sm + KVOFF;                       // 32KB O-transpose buffer
    const int q  = mr * 32 + l31;
    const int q2 = tid >> 3;
    const int d0b = (tid & 7) * 64;               // byte offset of 16-float chunk

    #pragma unroll 1
    for (int jg = 0; jg < 6; ++jg) {
        #pragma unroll
        for (int g = 0; g < 4; ++g) {
            int d0 = nc * 32 + 8 * g + 4 * hh;
            f32x4v o4 = { acc[jg][4 * g + 0] * rinv, acc[jg][4 * g + 1] * rinv,
                          acc[jg][4 * g + 2] * rinv, acc[jg][4 * g + 3] * rinv };
            *(f32x4v*)(obl + q * 512 + ((d0 * 4) ^ ((q & 7) << 4))) = o4;
        }
        __syncthreads();
        #pragma unroll
        for (int i = 0; i < 4; ++i) {
            f32x4v o = *(const f32x4v*)(obl + q2 * 512 + ((d0b + i * 16) ^ ((q2 & 7) << 4)));
            *(f32x4v*)(ob + (size_t)q2 * 768 + jg * 128 + (d0b >> 2) + i * 4) = o;
        }
        __syncthreads();
    }
    #undef STAGE16
}

// ============================ fallback (round-2 kernel) ============================
__device__ __forceinline__ void fb_stage_load(f32x4v (&vr)[2][4], const float* __restrict__ Vg,
                                              size_t kvbase, int srg, int scg, int ch) {
    #pragma unroll
    for (int i2 = 0; i2 < 2; ++i2) {
        const float* vp = Vg + kvbase + (size_t)(srg * 4) * 768 + ch * 128 + (scg + i2 * 16) * 4;
        #pragma unroll
        for (int rr = 0; rr < 4; ++rr)
            vr[i2][rr] = *(const f32x4v*)(vp + (size_t)rr * 768);
    }
}
__device__ __forceinline__ void fb_stage_write(const f32x4v (&vr)[2][4], char* Vb, int srg, int scg) {
    #pragma unroll
    for (int i2 = 0; i2 < 2; ++i2) {
        int cg = scg + i2 * 16;
        #pragma unroll
        for (int q4 = 0; q4 < 4; ++q4) {
            int drow = cg * 4 + q4;
            bf16x4 hv = { (__bf16)vr[i2][0][q4], (__bf16)vr[i2][1][q4],
                          (__bf16)vr[i2][2][q4], (__bf16)vr[i2][3][q4] };
            *(bf16x4*)(Vb + drow * 256 + ((srg * 8) ^ ((drow & 15) << 4))) = hv;
        }
    }
}
#define FB_OFF_V  98304
#define FB_OFF_P  131072
#define FB_OFF_RM 147456
#define FB_OFF_RL 148480
#define FB_LDS    149504
__global__ __launch_bounds__(512) void lsa_fb(
    const float* __restrict__ Qg, const float* __restrict__ Kg,
    const float* __restrict__ Vg, const float* __restrict__ Tg,
    float* __restrict__ Og)
{
    extern __shared__ char smem[];
    char*  Qb    = smem;
    char*  Vb    = smem + FB_OFF_V;
    char*  Pb    = smem + FB_OFF_P;
    float* red_m = (float*)(smem + FB_OFF_RM);
    float* red_l = (float*)(smem + FB_OFF_RL);
    const int tid  = threadIdx.x;
    const int lane = tid & 63;
    const int w    = tid >> 6;
    const int mr   = w & 1;
    const int nc   = w >> 1;
    const int half = lane >> 5;
    const int l31  = lane & 31;
    int id = blockIdx.x, xcd = id & 7, jj = id >> 3;
    int batch = (jj >> 5) * 16 + xcd * 2 + ((jj >> 4) & 1);
    int qt = jj & 15;
    const float scale2 = 1.4426950408889634f / Tg[0];
    {
        const float* qp   = Qg + ((size_t)batch * 1024 + (size_t)qt * 64) * 768;
        int   row   = tid >> 3, c0 = tid & 7;
        const float* qrow = qp + (size_t)row * 768;
        char* qdst  = Qb + row * 1536;
        int   rx    = (row & 15) << 4;
        #pragma unroll
        for (int j = 0; j < 24; ++j) {
            int c4 = c0 + j * 8;
            f32x4v q4 = *(const f32x4v*)(qrow + c4 * 4);
            bf16x4 hq = { (__bf16)(q4[0] * scale2), (__bf16)(q4[1] * scale2),
                          (__bf16)(q4[2] * scale2), (__bf16)(q4[3] * scale2) };
            *(bf16x4*)(qdst + ((c4 * 8) ^ rx)) = hq;
        }
    }
    __syncthreads();
    f32x16 acc[6];
    #pragma unroll
    for (int ch = 0; ch < 6; ++ch)
        #pragma unroll
        for (int r = 0; r < 16; ++r) acc[ch][r] = 0.0f;
    float m_st = -1e30f, l_st = 0.0f;
    const int  qrow_g = mr * 32 + l31;
    const int  qglob  = qt * 64 + qrow_g;
    char*      qfbase = Qb + qrow_g * 1536;
    const int  qx     = (qrow_g & 15) << 4;
    char*      pfbase = Pb + qrow_g * 256;
    const int  vrow   = nc * 32 + l31;
    char*      vfbase = Vb + vrow * 256;
    const int  vx     = (vrow & 15) << 4;
    const int  diag_tile = qt >> 1;
    const int  srg = tid & 31, scg = tid >> 5;
    #pragma unroll 1
    for (int t = 0; t < 8; ++t) {
        const size_t kvbase = ((size_t)batch * 1024 + (size_t)t * 128) * 768;
        f32x16 s;
        #pragma unroll
        for (int r = 0; r < 16; ++r) s[r] = 0.0f;
        const float* kptr = Kg + kvbase + (size_t)(nc * 32 + l31) * 768 + 8 * half;
        #pragma unroll
        for (int ch = 0; ch < 6; ++ch) {
            #pragma unroll
            for (int ks = 0; ks < 8; ++ks) {
                f32x4v k0 = *(const f32x4v*)(kptr + ch * 128 + ks * 16);
                f32x4v k1 = *(const f32x4v*)(kptr + ch * 128 + ks * 16 + 4);
                bf16x8 kf = { (__bf16)k0[0], (__bf16)k0[1], (__bf16)k0[2], (__bf16)k0[3],
                              (__bf16)k1[0], (__bf16)k1[1], (__bf16)k1[2], (__bf16)k1[3] };
                bf16x8 qf = *(const bf16x8*)(qfbase + ((ch * 256 + ks * 32 + half * 16) ^ qx));
                s = __builtin_amdgcn_mfma_f32_32x32x16_bf16(kf, qf, s, 0, 0, 0);
            }
        }
        if (t == diag_tile) {
            #pragma unroll
            for (int r = 0; r < 16; ++r) {
                int kvg = t * 128 + nc * 32 + (r & 3) + 8 * (r >> 2) + 4 * half;
                if (kvg == qglob) s[r] = -1e30f;
            }
        }
        f32x4v vr[2][4];
        fb_stage_load(vr, Vg, kvbase, srg, scg, 0);
        float pm = s[0];
        #pragma unroll
        for (int r = 1; r < 16; ++r) pm = fmaxf(pm, s[r]);
        pm = fmaxf(pm, __shfl_xor(pm, 32, 64));
        if (half == 0) red_m[qrow_g * 4 + nc] = pm;
        __syncthreads();
        f32x4v m4 = *(const f32x4v*)(red_m + qrow_g * 4);
        float mnew = fmaxf(fmaxf(m4[0], m4[1]), fmaxf(m4[2], m4[3]));
        mnew = fmaxf(mnew, m_st);
        float cf = __builtin_amdgcn_exp2f(m_st - mnew);
        m_st = mnew;
        float pl = 0.0f;
        #pragma unroll
        for (int r = 0; r < 16; ++r) {
            float e = __builtin_amdgcn_exp2f(s[r] - mnew);
            s[r] = e; pl += e;
        }
        pl += __shfl_xor(pl, 32, 64);
        l_st = l_st * cf + pl;
        #pragma unroll
        for (int ch = 0; ch < 6; ++ch)
            #pragma unroll
            for (int r = 0; r < 16; ++r) acc[ch][r] *= cf;
        #pragma unroll
        for (int g = 0; g < 4; ++g) {
            bf16x4 hp = { (__bf16)s[4*g+0], (__bf16)s[4*g+1],
                          (__bf16)s[4*g+2], (__bf16)s[4*g+3] };
            *(bf16x4*)(pfbase + ((nc * 64 + g * 16 + half * 8) ^ qx)) = hp;
        }
        fb_stage_write(vr, Vb, srg, scg);
        __syncthreads();
        bf16x8 pa[8];
        #pragma unroll
        for (int ks = 0; ks < 8; ++ks)
            pa[ks] = *(const bf16x8*)(pfbase + ((ks * 32 + half * 16) ^ qx));
        #pragma unroll
        for (int ch = 0; ch < 6; ++ch) {
            if (ch < 5) fb_stage_load(vr, Vg, kvbase, srg, scg, ch + 1);
            #pragma unroll
            for (int ks = 0; ks < 8; ++ks) {
                bf16x8 vf = *(const bf16x8*)(vfbase + ((ks * 32 + half * 16) ^ vx));
                acc[ch] = __builtin_amdgcn_mfma_f32_32x32x16_bf16(vf, pa[ks], acc[ch], 0, 0, 0);
            }
            if (ch < 5) {
                __syncthreads();
                fb_stage_write(vr, Vb, srg, scg);
                __syncthreads();
            }
        }
    }
    if (half == 0) red_l[qrow_g * 4 + nc] = l_st;
    __syncthreads();
    f32x4v l4 = *(const f32x4v*)(red_l + qrow_g * 4);
    float rinv = 1.0f / (l4[0] + l4[1] + l4[2] + l4[3]);
    float* op = Og + ((size_t)batch * 1024 + (size_t)qglob) * 768;
    #pragma unroll
    for (int ch = 0; ch < 6; ++ch)
        #pragma unroll
        for (int g = 0; g < 4; ++g) {
            f32x4v o4 = { acc[ch][4*g+0] * rinv, acc[ch][4*g+1] * rinv,
                          acc[ch][4*g+2] * rinv, acc[ch][4*g+3] * rinv };
            *(f32x4v*)(op + ch * 128 + nc * 32 + g * 8 + half * 4) = o4;
        }
}

extern "C" void kernel_launch(void* const* d_in, const int* in_sizes, int n_in,
                              void* d_out, int out_size, void* d_ws, size_t ws_size,
                              hipStream_t stream) {
    (void)in_sizes; (void)n_in; (void)out_size;
    const float* Q = (const float*)d_in[0];
    const float* K = (const float*)d_in[1];
    const float* V = (const float*)d_in[2];
    const float* T = (const float*)d_in[3];
    float* O = (float*)d_out;
    if (ws_size >= WS_NEEDED) {
        unsigned short* Qws = (unsigned short*)((char*)d_ws + WS_Q);
        unsigned short* Kws = (unsigned short*)((char*)d_ws + WS_K);
        unsigned short* Vws = (unsigned short*)((char*)d_ws + WS_V);
        prep_q<<<dim3(1024), dim3(256), 0, stream>>>(Q, T, Qws);
        prep_k<<<dim3(512),  dim3(512), 0, stream>>>(K, Kws);
        prep_v<<<dim3(512),  dim3(512), 0, stream>>>(V, Vws);
        lsa_main<<<dim3(1024), dim3(512), LDS_MAIN, stream>>>(Qws, Kws, Vws, O);
    } else {
        lsa_fb<<<dim3(1024), dim3(512), FB_LDS, stream>>>(Q, K, V, T, O);
    }
}

// Round 4
// 952.295 us; speedup vs baseline: 1.7492x; 1.7492x over previous
//
#include <hip/hip_runtime.h>

// LSA fused attention: out = softmax(QK^T/temp, diag=-inf) @ V
// B=64, N=1024, D=768, fp32 I/O, bf16 MFMA 32x32x16.
//
// 3 prepass kernels rewrite Q(scaled),K,V as MFMA-fragment-ordered bf16
// images in d_ws (verified in R3). Main kernel (new): K/V frags loaded
// DIRECTLY global->VGPR (coalesced base+lane*16, served by XCD-local L2;
// each image byte read once per block). Q resident in LDS; P exchanged
// via LDS in fragment layout. 2 barriers per tile. BKV=256, per wave:
// 32 kv x 64 q (QK) and 96 d x 64 q (PV). All acc indexing static.

typedef __bf16 bf16x8 __attribute__((ext_vector_type(8)));
typedef __bf16 bf16x4 __attribute__((ext_vector_type(4)));
typedef float  f32x16 __attribute__((ext_vector_type(16)));
typedef float  f32x4v __attribute__((ext_vector_type(4)));

#define WS_Q 0UL
#define WS_K 100663296UL
#define WS_V 201326592UL
#define WS_NEEDED 301989888UL

#define QOFF   0          // 96 KB Q frag image (resident; reused as O-transpose)
#define POFF   98304      // 32 KB P frag blocks [ksl*2+qg]
#define REDOFF 131072     // red_m 2KB + red_l 2KB
#define LDS_MAIN 135168

__device__ __forceinline__ void gld16(const void* g, const char* l) {
    __builtin_amdgcn_global_load_lds(
        (const __attribute__((address_space(1))) unsigned int*)g,
        (__attribute__((address_space(3))) unsigned int*)(l), 16, 0, 0);
}

// ============================ prepass: Q ============================
__global__ __launch_bounds__(256) void prep_q(const float* __restrict__ Qg,
                                              const float* __restrict__ Tg,
                                              unsigned short* __restrict__ Qws) {
    __shared__ __align__(16) unsigned short L[64 * 72];   // stride 144B
    const int bid = blockIdx.x;            // b*16 + qt
    const int tid = threadIdx.x;
    const float scale2 = 1.4426950408889634f / Tg[0];     // log2(e)/temp
    const float* src = Qg + (size_t)bid * 64 * 768;
    char* outb = (char*)Qws + (size_t)bid * 98304;
    const int q  = tid >> 2;
    const int k0 = (tid & 3) * 16;
    #pragma unroll 1
    for (int st = 0; st < 12; ++st) {
        #pragma unroll
        for (int i = 0; i < 4; ++i) {
            f32x4v v = *(const f32x4v*)(src + (size_t)q * 768 + st * 64 + k0 + i * 4);
            bf16x4 hb = { (__bf16)(v[0] * scale2), (__bf16)(v[1] * scale2),
                          (__bf16)(v[2] * scale2), (__bf16)(v[3] * scale2) };
            *(bf16x4*)((char*)L + q * 144 + (k0 + i * 4) * 2) = hb;
        }
        __syncthreads();
        #pragma unroll
        for (int i = 0; i < 2; ++i) {
            int u = tid * 2 + i;                       // [0,512)
            int ks = u >> 7, mrr = (u >> 6) & 1, l = u & 63;
            bf16x8 f = *(const bf16x8*)((char*)L + (mrr * 32 + (l & 31)) * 144
                                        + ks * 32 + 16 * (l >> 5));
            *(bf16x8*)(outb + (size_t)st * 8192 + u * 16) = f;
        }
        __syncthreads();
    }
}

// ============================ prepass: K ============================
__global__ __launch_bounds__(512) void prep_k(const float* __restrict__ Kg,
                                              unsigned short* __restrict__ Kws) {
    __shared__ __align__(16) unsigned short L[128 * 72];  // stride 144B
    const int bid = blockIdx.x;            // b*8 + t
    const int tid = threadIdx.x;
    const float* src = Kg + (size_t)bid * 128 * 768;
    char* outb = (char*)Kws + (size_t)bid * 196608;
    const int kv = tid >> 2;
    const int k0 = (tid & 3) * 16;
    #pragma unroll 1
    for (int st = 0; st < 12; ++st) {
        #pragma unroll
        for (int i = 0; i < 4; ++i) {
            f32x4v v = *(const f32x4v*)(src + (size_t)kv * 768 + st * 64 + k0 + i * 4);
            bf16x4 hb = { (__bf16)v[0], (__bf16)v[1], (__bf16)v[2], (__bf16)v[3] };
            *(bf16x4*)((char*)L + kv * 144 + (k0 + i * 4) * 2) = hb;
        }
        __syncthreads();
        #pragma unroll
        for (int i = 0; i < 2; ++i) {
            int u = tid * 2 + i;                       // [0,1024)
            int ks = u >> 8, ncc = (u >> 6) & 3, l = u & 63;
            bf16x8 f = *(const bf16x8*)((char*)L + (ncc * 32 + (l & 31)) * 144
                                        + ks * 32 + 16 * (l >> 5));
            *(bf16x8*)(outb + (size_t)st * 16384 + u * 16) = f;
        }
        __syncthreads();
    }
}

// ============================ prepass: V (transpose) ============================
__global__ __launch_bounds__(512) void prep_v(const float* __restrict__ Vg,
                                              unsigned short* __restrict__ Vws) {
    __shared__ __align__(16) unsigned short L[128 * 136]; // V^T [d 128][kv], stride 272B
    const int bid = blockIdx.x;            // b*8 + t
    const int tid = threadIdx.x;
    const float* src = Vg + (size_t)bid * 128 * 768;
    char* outb = (char*)Vws + (size_t)bid * 196608;
    const int srg = tid & 31, scg = tid >> 5;
    #pragma unroll 1
    for (int jg = 0; jg < 6; ++jg) {
        #pragma unroll
        for (int i2 = 0; i2 < 2; ++i2) {
            int cg = scg + i2 * 16;
            const float* vp = src + (size_t)(srg * 4) * 768 + jg * 128 + cg * 4;
            f32x4v a0 = *(const f32x4v*)(vp);
            f32x4v a1 = *(const f32x4v*)(vp + 768);
            f32x4v a2 = *(const f32x4v*)(vp + 1536);
            f32x4v a3 = *(const f32x4v*)(vp + 2304);
            #pragma unroll
            for (int c = 0; c < 4; ++c) {
                int d = cg * 4 + c;
                bf16x4 hb = { (__bf16)a0[c], (__bf16)a1[c], (__bf16)a2[c], (__bf16)a3[c] };
                *(bf16x4*)((char*)L + d * 272 + srg * 8) = hb;
            }
        }
        __syncthreads();
        #pragma unroll
        for (int i = 0; i < 4; ++i) {
            int u = tid * 4 + i;                       // [0,2048)
            int kh = u >> 10, ks = (u >> 8) & 3, ncc = (u >> 6) & 3, l = u & 63;
            bf16x8 f = *(const bf16x8*)((char*)L + (ncc * 32 + (l & 31)) * 272
                                        + kh * 128 + ks * 32 + 16 * (l >> 5));
            *(bf16x8*)(outb + (size_t)(jg * 2 + kh) * 16384 + (u & 1023) * 16) = f;
        }
        __syncthreads();
    }
}

// ============================ main kernel ============================
// K frag addr (tile t2, wave w, slot sl 0..47):
//   kimg + (t2*2 + (w>>2))*196608 + (sl>>2)*16384 + ((sl&3)*4 + (w&3))*1024 + lane*16
// V frag addr (t2, dgi = w*3+g3, ksl 0..15):
//   vimg + (t2*2 + (ksl>>3))*196608 + (((dgi>>2)*2 + ((ksl>>2)&1)))*16384
//        + ((ksl&3)*4 + (dgi&3))*1024 + lane*16
#define OFFK(sl) ((size_t)((sl) >> 2) * 16384 + (size_t)((sl) & 3) * 4096)
#define OFFV(ksl) ((size_t)((ksl) >> 3) * 196608 + (size_t)(((ksl) >> 2) & 1) * 16384 \
                   + (size_t)((ksl) & 3) * 4096)

__global__ __launch_bounds__(512, 2) void lsa_main(
    const unsigned short* __restrict__ Qws, const unsigned short* __restrict__ Kws,
    const unsigned short* __restrict__ Vws, float* __restrict__ Og)
{
    extern __shared__ char sm[];
    const int tid  = threadIdx.x;
    const int lane = tid & 63;
    const int w    = tid >> 6;
    const int hh   = lane >> 5;
    const int l31  = lane & 31;

    int id = blockIdx.x;
    int xcd = id & 7, jj = id >> 3;
    int batch = (jj >> 5) * 16 + xcd * 2 + ((jj >> 4) & 1);
    int qt = jj & 15;

    const char* qimg = (const char*)Qws + (size_t)(batch * 16 + qt) * 98304;
    const char* kimg = (const char*)Kws + (size_t)batch * 1572864;
    const char* vimg = (const char*)Vws + (size_t)batch * 1572864;
    float* redm = (float*)(sm + REDOFF);
    float* redl = (float*)(sm + REDOFF + 2048);

    // ---- stage Q image (96 KB) into LDS ----
    #pragma unroll
    for (int i = 0; i < 12; ++i)
        gld16(qimg + i * 8192 + tid * 16, sm + QOFF + i * 8192 + w * 1024);
    __syncthreads();

    f32x16 acc[3][2];
    #pragma unroll
    for (int g3 = 0; g3 < 3; ++g3)
        #pragma unroll
        for (int qg = 0; qg < 2; ++qg)
            #pragma unroll
            for (int r = 0; r < 16; ++r) acc[g3][qg][r] = 0.0f;
    float m_st[2] = { -3e38f, -3e38f };
    float l_st[2] = { 0.0f, 0.0f };

    // per-wave bases
    const size_t kwoff = (size_t)(w >> 2) * 196608 + (size_t)(w & 3) * 1024
                         + (size_t)lane * 16;
    size_t voff3[3];
    #pragma unroll
    for (int g3 = 0; g3 < 3; ++g3) {
        int dgi = w * 3 + g3;
        voff3[g3] = (size_t)(dgi >> 2) * 32768 + (size_t)(dgi & 3) * 1024
                    + (size_t)lane * 16;
    }
    const int diag_t2 = qt >> 2;

    #pragma unroll 1
    for (int t2 = 0; t2 < 4; ++t2) {
        // ================= QK^T (barrier-free, global->reg K frags) =================
        const char* kb = kimg + (size_t)t2 * 393216 + kwoff;
        f32x16 s[2];
        #pragma unroll
        for (int qg = 0; qg < 2; ++qg)
            #pragma unroll
            for (int r = 0; r < 16; ++r) s[qg][r] = 0.0f;

        bf16x8 kbf[3][4];
        #pragma unroll
        for (int j = 0; j < 4; ++j) kbf[0][j] = *(const bf16x8*)(kb + OFFK(j));
        #pragma unroll
        for (int j = 0; j < 4; ++j) kbf[1][j] = *(const bf16x8*)(kb + OFFK(4 + j));

        #pragma unroll
        for (int c = 0; c < 12; ++c) {
            if (c < 10) {
                #pragma unroll
                for (int j = 0; j < 4; ++j)
                    kbf[(c + 2) % 3][j] = *(const bf16x8*)(kb + OFFK((c + 2) * 4 + j));
            }
            #pragma unroll
            for (int j = 0; j < 4; ++j) {
                const int sl = c * 4 + j;
                bf16x8 qf0 = *(const bf16x8*)(sm + QOFF + (sl * 2 + 0) * 1024 + lane * 16);
                bf16x8 qf1 = *(const bf16x8*)(sm + QOFF + (sl * 2 + 1) * 1024 + lane * 16);
                s[0] = __builtin_amdgcn_mfma_f32_32x32x16_bf16(kbf[c % 3][j], qf0, s[0], 0, 0, 0);
                s[1] = __builtin_amdgcn_mfma_f32_32x32x16_bf16(kbf[c % 3][j], qf1, s[1], 0, 0, 0);
            }
        }

        // diagonal self-exclusion
        if (t2 == diag_t2) {
            #pragma unroll
            for (int qg = 0; qg < 2; ++qg)
                #pragma unroll
                for (int r = 0; r < 16; ++r) {
                    int kvg = t2 * 256 + w * 32 + (r & 3) + 8 * (r >> 2) + 4 * hh;
                    if (kvg == qt * 64 + qg * 32 + l31) s[qg][r] = -3e38f;
                }
        }

        // ================= online softmax (2 q-rows per lane) =================
        #pragma unroll
        for (int qg = 0; qg < 2; ++qg) {
            float pm = s[qg][0];
            #pragma unroll
            for (int r = 1; r < 16; ++r) pm = fmaxf(pm, s[qg][r]);
            pm = fmaxf(pm, __shfl_xor(pm, 32, 64));
            if (hh == 0) redm[(qg * 32 + l31) * 8 + w] = pm;
        }
        __syncthreads();                       // barrier 1
        float cf[2];
        #pragma unroll
        for (int qg = 0; qg < 2; ++qg) {
            const float* rp = redm + (qg * 32 + l31) * 8;
            f32x4v a = *(const f32x4v*)rp;
            f32x4v b = *(const f32x4v*)(rp + 4);
            float mn = fmaxf(fmaxf(fmaxf(a[0], a[1]), fmaxf(a[2], a[3])),
                             fmaxf(fmaxf(b[0], b[1]), fmaxf(b[2], b[3])));
            mn = fmaxf(mn, m_st[qg]);
            cf[qg] = __builtin_amdgcn_exp2f(m_st[qg] - mn);
            m_st[qg] = mn;
            float pl = 0.0f;
            #pragma unroll
            for (int r = 0; r < 16; ++r) {
                float e = __builtin_amdgcn_exp2f(s[qg][r] - mn);
                s[qg][r] = e; pl += e;
            }
            pl += __shfl_xor(pl, 32, 64);
            l_st[qg] = l_st[qg] * cf[qg] + pl;
        }
        #pragma unroll
        for (int g3 = 0; g3 < 3; ++g3)
            #pragma unroll
            for (int qg = 0; qg < 2; ++qg)
                #pragma unroll
                for (int r = 0; r < 16; ++r) acc[g3][qg][r] *= cf[qg];

        // P -> fragment layout in LDS: block (ksl*2+qg), lane (hfrag*32+l31), j0=4*hh
        #pragma unroll
        for (int qg = 0; qg < 2; ++qg)
            #pragma unroll
            for (int g = 0; g < 4; ++g) {
                bf16x4 p4 = { (__bf16)s[qg][4 * g + 0], (__bf16)s[qg][4 * g + 1],
                              (__bf16)s[qg][4 * g + 2], (__bf16)s[qg][4 * g + 3] };
                int blk = (2 * w + (g >> 1)) * 2 + qg;
                int lidx = (g & 1) * 32 + l31;
                *(bf16x4*)(sm + POFF + blk * 1024 + lidx * 16 + hh * 8) = p4;
            }
        __syncthreads();                       // barrier 2

        // ================= P @ V (barrier-free, global->reg V frags) =================
        const char* vb = vimg + (size_t)t2 * 393216;
        bf16x8 vbf[3][3];
        #pragma unroll
        for (int g3 = 0; g3 < 3; ++g3) vbf[0][g3] = *(const bf16x8*)(vb + voff3[g3] + OFFV(0));
        #pragma unroll
        for (int g3 = 0; g3 < 3; ++g3) vbf[1][g3] = *(const bf16x8*)(vb + voff3[g3] + OFFV(1));

        #pragma unroll
        for (int ksl = 0; ksl < 16; ++ksl) {
            if (ksl < 14) {
                #pragma unroll
                for (int g3 = 0; g3 < 3; ++g3)
                    vbf[(ksl + 2) % 3][g3] = *(const bf16x8*)(vb + voff3[g3] + OFFV(ksl + 2));
            }
            bf16x8 pa0 = *(const bf16x8*)(sm + POFF + (ksl * 2 + 0) * 1024 + lane * 16);
            bf16x8 pa1 = *(const bf16x8*)(sm + POFF + (ksl * 2 + 1) * 1024 + lane * 16);
            #pragma unroll
            for (int g3 = 0; g3 < 3; ++g3) {
                acc[g3][0] = __builtin_amdgcn_mfma_f32_32x32x16_bf16(vbf[ksl % 3][g3], pa0, acc[g3][0], 0, 0, 0);
                acc[g3][1] = __builtin_amdgcn_mfma_f32_32x32x16_bf16(vbf[ksl % 3][g3], pa1, acc[g3][1], 0, 0, 0);
            }
        }
        // P overwrite next tile is guarded by barrier 1+2 ordering (see analysis)
    }

    // ================= epilogue =================
    #pragma unroll
    for (int qg = 0; qg < 2; ++qg)
        if (hh == 0) redl[(qg * 32 + l31) * 8 + w] = l_st[qg];
    __syncthreads();
    float rinv[2];
    #pragma unroll
    for (int qg = 0; qg < 2; ++qg) {
        const float* rp = redl + (qg * 32 + l31) * 8;
        f32x4v a = *(const f32x4v*)rp;
        f32x4v b = *(const f32x4v*)(rp + 4);
        rinv[qg] = 1.0f / (a[0] + a[1] + a[2] + a[3] + b[0] + b[1] + b[2] + b[3]);
    }

    char* obt = sm + QOFF;                     // reuse Q space: [64 q][256 d] f32, XOR swizzle
    const size_t orow = (size_t)batch * 1024 + (size_t)qt * 64;
    const int q2 = tid >> 3, c8 = tid & 7;

    #pragma unroll
    for (int g3 = 0; g3 < 3; ++g3) {
        __syncthreads();                       // previous pass reads done
        #pragma unroll
        for (int qg = 0; qg < 2; ++qg) {
            int q = qg * 32 + l31;
            int qx = (q & 15) << 4;
            #pragma unroll
            for (int g = 0; g < 4; ++g) {
                f32x4v o4 = { acc[g3][qg][4 * g + 0] * rinv[qg],
                              acc[g3][qg][4 * g + 1] * rinv[qg],
                              acc[g3][qg][4 * g + 2] * rinv[qg],
                              acc[g3][qg][4 * g + 3] * rinv[qg] };
                int dloc = w * 32 + 8 * g + 4 * hh;
                *(f32x4v*)(obt + q * 1024 + ((dloc * 4) ^ qx)) = o4;
            }
        }
        __syncthreads();
        #pragma unroll
        for (int i = 0; i < 8; ++i) {
            int db = c8 * 128 + i * 16;
            f32x4v o = *(const f32x4v*)(obt + q2 * 1024 + (db ^ ((q2 & 15) << 4)));
            int dg = c8 * 96 + g3 * 32 + i * 4;
            *(f32x4v*)(Og + (orow + q2) * 768 + dg) = o;
        }
    }
}

// ============================ fallback (round-2 kernel) ============================
__device__ __forceinline__ void fb_stage_load(f32x4v (&vr)[2][4], const float* __restrict__ Vg,
                                              size_t kvbase, int srg, int scg, int ch) {
    #pragma unroll
    for (int i2 = 0; i2 < 2; ++i2) {
        const float* vp = Vg + kvbase + (size_t)(srg * 4) * 768 + ch * 128 + (scg + i2 * 16) * 4;
        #pragma unroll
        for (int rr = 0; rr < 4; ++rr)
            vr[i2][rr] = *(const f32x4v*)(vp + (size_t)rr * 768);
    }
}
__device__ __forceinline__ void fb_stage_write(const f32x4v (&vr)[2][4], char* Vb, int srg, int scg) {
    #pragma unroll
    for (int i2 = 0; i2 < 2; ++i2) {
        int cg = scg + i2 * 16;
        #pragma unroll
        for (int q4 = 0; q4 < 4; ++q4) {
            int drow = cg * 4 + q4;
            bf16x4 hv = { (__bf16)vr[i2][0][q4], (__bf16)vr[i2][1][q4],
                          (__bf16)vr[i2][2][q4], (__bf16)vr[i2][3][q4] };
            *(bf16x4*)(Vb + drow * 256 + ((srg * 8) ^ ((drow & 15) << 4))) = hv;
        }
    }
}
#define FB_OFF_V  98304
#define FB_OFF_P  131072
#define FB_OFF_RM 147456
#define FB_OFF_RL 148480
#define FB_LDS    149504
__global__ __launch_bounds__(512) void lsa_fb(
    const float* __restrict__ Qg, const float* __restrict__ Kg,
    const float* __restrict__ Vg, const float* __restrict__ Tg,
    float* __restrict__ Og)
{
    extern __shared__ char smem[];
    char*  Qb    = smem;
    char*  Vb    = smem + FB_OFF_V;
    char*  Pb    = smem + FB_OFF_P;
    float* red_m = (float*)(smem + FB_OFF_RM);
    float* red_l = (float*)(smem + FB_OFF_RL);
    const int tid  = threadIdx.x;
    const int lane = tid & 63;
    const int w    = tid >> 6;
    const int mr   = w & 1;
    const int nc   = w >> 1;
    const int half = lane >> 5;
    const int l31  = lane & 31;
    int id = blockIdx.x, xcd = id & 7, jj = id >> 3;
    int batch = (jj >> 5) * 16 + xcd * 2 + ((jj >> 4) & 1);
    int qt = jj & 15;
    const float scale2 = 1.4426950408889634f / Tg[0];
    {
        const float* qp   = Qg + ((size_t)batch * 1024 + (size_t)qt * 64) * 768;
        int   row   = tid >> 3, c0 = tid & 7;
        const float* qrow = qp + (size_t)row * 768;
        char* qdst  = Qb + row * 1536;
        int   rx    = (row & 15) << 4;
        #pragma unroll
        for (int j = 0; j < 24; ++j) {
            int c4 = c0 + j * 8;
            f32x4v q4 = *(const f32x4v*)(qrow + c4 * 4);
            bf16x4 hq = { (__bf16)(q4[0] * scale2), (__bf16)(q4[1] * scale2),
                          (__bf16)(q4[2] * scale2), (__bf16)(q4[3] * scale2) };
            *(bf16x4*)(qdst + ((c4 * 8) ^ rx)) = hq;
        }
    }
    __syncthreads();
    f32x16 acc[6];
    #pragma unroll
    for (int ch = 0; ch < 6; ++ch)
        #pragma unroll
        for (int r = 0; r < 16; ++r) acc[ch][r] = 0.0f;
    float m_st = -3e38f, l_st = 0.0f;
    const int  qrow_g = mr * 32 + l31;
    const int  qglob  = qt * 64 + qrow_g;
    char*      qfbase = Qb + qrow_g * 1536;
    const int  qx     = (qrow_g & 15) << 4;
    char*      pfbase = Pb + qrow_g * 256;
    const int  vrow   = nc * 32 + l31;
    char*      vfbase = Vb + vrow * 256;
    const int  vx     = (vrow & 15) << 4;
    const int  diag_tile = qt >> 1;
    const int  srg = tid & 31, scg = tid >> 5;
    #pragma unroll 1
    for (int t = 0; t < 8; ++t) {
        const size_t kvbase = ((size_t)batch * 1024 + (size_t)t * 128) * 768;
        f32x16 s;
        #pragma unroll
        for (int r = 0; r < 16; ++r) s[r] = 0.0f;
        const float* kptr = Kg + kvbase + (size_t)(nc * 32 + l31) * 768 + 8 * half;
        #pragma unroll
        for (int ch = 0; ch < 6; ++ch) {
            #pragma unroll
            for (int ks = 0; ks < 8; ++ks) {
                f32x4v k0 = *(const f32x4v*)(kptr + ch * 128 + ks * 16);
                f32x4v k1 = *(const f32x4v*)(kptr + ch * 128 + ks * 16 + 4);
                bf16x8 kf = { (__bf16)k0[0], (__bf16)k0[1], (__bf16)k0[2], (__bf16)k0[3],
                              (__bf16)k1[0], (__bf16)k1[1], (__bf16)k1[2], (__bf16)k1[3] };
                bf16x8 qf = *(const bf16x8*)(qfbase + ((ch * 256 + ks * 32 + half * 16) ^ qx));
                s = __builtin_amdgcn_mfma_f32_32x32x16_bf16(kf, qf, s, 0, 0, 0);
            }
        }
        if (t == diag_tile) {
            #pragma unroll
            for (int r = 0; r < 16; ++r) {
                int kvg = t * 128 + nc * 32 + (r & 3) + 8 * (r >> 2) + 4 * half;
                if (kvg == qglob) s[r] = -3e38f;
            }
        }
        f32x4v vr[2][4];
        fb_stage_load(vr, Vg, kvbase, srg, scg, 0);
        float pm = s[0];
        #pragma unroll
        for (int r = 1; r < 16; ++r) pm = fmaxf(pm, s[r]);
        pm = fmaxf(pm, __shfl_xor(pm, 32, 64));
        if (half == 0) red_m[qrow_g * 4 + nc] = pm;
        __syncthreads();
        f32x4v m4 = *(const f32x4v*)(red_m + qrow_g * 4);
        float mnew = fmaxf(fmaxf(m4[0], m4[1]), fmaxf(m4[2], m4[3]));
        mnew = fmaxf(mnew, m_st);
        float cf = __builtin_amdgcn_exp2f(m_st - mnew);
        m_st = mnew;
        float pl = 0.0f;
        #pragma unroll
        for (int r = 0; r < 16; ++r) {
            float e = __builtin_amdgcn_exp2f(s[r] - mnew);
            s[r] = e; pl += e;
        }
        pl += __shfl_xor(pl, 32, 64);
        l_st = l_st * cf + pl;
        #pragma unroll
        for (int ch = 0; ch < 6; ++ch)
            #pragma unroll
            for (int r = 0; r < 16; ++r) acc[ch][r] *= cf;
        #pragma unroll
        for (int g = 0; g < 4; ++g) {
            bf16x4 hp = { (__bf16)s[4*g+0], (__bf16)s[4*g+1],
                          (__bf16)s[4*g+2], (__bf16)s[4*g+3] };
            *(bf16x4*)(pfbase + ((nc * 64 + g * 16 + half * 8) ^ qx)) = hp;
        }
        fb_stage_write(vr, Vb, srg, scg);
        __syncthreads();
        bf16x8 pa[8];
        #pragma unroll
        for (int ks = 0; ks < 8; ++ks)
            pa[ks] = *(const bf16x8*)(pfbase + ((ks * 32 + half * 16) ^ qx));
        #pragma unroll
        for (int ch = 0; ch < 6; ++ch) {
            if (ch < 5) fb_stage_load(vr, Vg, kvbase, srg, scg, ch + 1);
            #pragma unroll
            for (int ks = 0; ks < 8; ++ks) {
                bf16x8 vf = *(const bf16x8*)(vfbase + ((ks * 32 + half * 16) ^ vx));
                acc[ch] = __builtin_amdgcn_mfma_f32_32x32x16_bf16(vf, pa[ks], acc[ch], 0, 0, 0);
            }
            if (ch < 5) {
                __syncthreads();
                fb_stage_write(vr, Vb, srg, scg);
                __syncthreads();
            }
        }
    }
    if (half == 0) red_l[qrow_g * 4 + nc] = l_st;
    __syncthreads();
    f32x4v l4 = *(const f32x4v*)(red_l + qrow_g * 4);
    float rinv = 1.0f / (l4[0] + l4[1] + l4[2] + l4[3]);
    float* op = Og + ((size_t)batch * 1024 + (size_t)qglob) * 768;
    #pragma unroll
    for (int ch = 0; ch < 6; ++ch)
        #pragma unroll
        for (int g = 0; g < 4; ++g) {
            f32x4v o4 = { acc[ch][4*g+0] * rinv, acc[ch][4*g+1] * rinv,
                          acc[ch][4*g+2] * rinv, acc[ch][4*g+3] * rinv };
            *(f32x4v*)(op + ch * 128 + nc * 32 + g * 8 + half * 4) = o4;
        }
}

extern "C" void kernel_launch(void* const* d_in, const int* in_sizes, int n_in,
                              void* d_out, int out_size, void* d_ws, size_t ws_size,
                              hipStream_t stream) {
    (void)in_sizes; (void)n_in; (void)out_size;
    const float* Q = (const float*)d_in[0];
    const float* K = (const float*)d_in[1];
    const float* V = (const float*)d_in[2];
    const float* T = (const float*)d_in[3];
    float* O = (float*)d_out;
    if (ws_size >= WS_NEEDED) {
        unsigned short* Qws = (unsigned short*)((char*)d_ws + WS_Q);
        unsigned short* Kws = (unsigned short*)((char*)d_ws + WS_K);
        unsigned short* Vws = (unsigned short*)((char*)d_ws + WS_V);
        prep_q<<<dim3(1024), dim3(256), 0, stream>>>(Q, T, Qws);
        prep_k<<<dim3(512),  dim3(512), 0, stream>>>(K, Kws);
        prep_v<<<dim3(512),  dim3(512), 0, stream>>>(V, Vws);
        lsa_main<<<dim3(1024), dim3(512), LDS_MAIN, stream>>>(Qws, Kws, Vws, O);
    } else {
        lsa_fb<<<dim3(1024), dim3(512), FB_LDS, stream>>>(Q, K, V, T, O);
    }
}

// Round 5
// 493.763 us; speedup vs baseline: 3.3737x; 1.9286x over previous
//
#include <hip/hip_runtime.h>

// LSA fused attention: out = softmax(QK^T/temp, diag=-inf) @ V
// B=64, N=1024, D=768, fp32 I/O, bf16 MFMA 32x32x16.
//
// 3 prepass kernels rewrite Q(scaled),K,V as MFMA-fragment-ordered bf16
// images in d_ws. Main kernel: K/V frags loaded DIRECTLY global->VGPR
// (coalesced base+lane*16, each image byte read once per block) with
// DEEP prefetch rings (K:8, V:4) to cover L2/L3 latency; V ring warmed
// before softmax; raw s_barrier + lgkmcnt-only waits keep prefetches
// alive across barriers; setprio around MFMA clusters. Q resident in
// LDS; P exchanged via LDS in fragment layout. All acc indexing static.

typedef __bf16 bf16x8 __attribute__((ext_vector_type(8)));
typedef __bf16 bf16x4 __attribute__((ext_vector_type(4)));
typedef float  f32x16 __attribute__((ext_vector_type(16)));
typedef float  f32x4v __attribute__((ext_vector_type(4)));

#define WS_Q 0UL
#define WS_K 100663296UL
#define WS_V 201326592UL
#define WS_NEEDED 301989888UL

#define QOFF   0          // 96 KB Q frag image (resident; reused as O-transpose)
#define POFF   98304      // 32 KB P frag blocks [ksl*2+qg]
#define REDOFF 131072     // red_m 2KB + red_l 2KB
#define LDS_MAIN 135168

__device__ __forceinline__ void gld16(const void* g, const char* l) {
    __builtin_amdgcn_global_load_lds(
        (const __attribute__((address_space(1))) unsigned int*)g,
        (__attribute__((address_space(3))) unsigned int*)(l), 16, 0, 0);
}

// ============================ prepass: Q ============================
__global__ __launch_bounds__(256) void prep_q(const float* __restrict__ Qg,
                                              const float* __restrict__ Tg,
                                              unsigned short* __restrict__ Qws) {
    __shared__ __align__(16) unsigned short L[64 * 72];   // stride 144B
    const int bid = blockIdx.x;            // b*16 + qt
    const int tid = threadIdx.x;
    const float scale2 = 1.4426950408889634f / Tg[0];     // log2(e)/temp
    const float* src = Qg + (size_t)bid * 64 * 768;
    char* outb = (char*)Qws + (size_t)bid * 98304;
    const int q  = tid >> 2;
    const int k0 = (tid & 3) * 16;
    #pragma unroll 1
    for (int st = 0; st < 12; ++st) {
        #pragma unroll
        for (int i = 0; i < 4; ++i) {
            f32x4v v = *(const f32x4v*)(src + (size_t)q * 768 + st * 64 + k0 + i * 4);
            bf16x4 hb = { (__bf16)(v[0] * scale2), (__bf16)(v[1] * scale2),
                          (__bf16)(v[2] * scale2), (__bf16)(v[3] * scale2) };
            *(bf16x4*)((char*)L + q * 144 + (k0 + i * 4) * 2) = hb;
        }
        __syncthreads();
        #pragma unroll
        for (int i = 0; i < 2; ++i) {
            int u = tid * 2 + i;                       // [0,512)
            int ks = u >> 7, mrr = (u >> 6) & 1, l = u & 63;
            bf16x8 f = *(const bf16x8*)((char*)L + (mrr * 32 + (l & 31)) * 144
                                        + ks * 32 + 16 * (l >> 5));
            *(bf16x8*)(outb + (size_t)st * 8192 + u * 16) = f;
        }
        __syncthreads();
    }
}

// ============================ prepass: K ============================
__global__ __launch_bounds__(512) void prep_k(const float* __restrict__ Kg,
                                              unsigned short* __restrict__ Kws) {
    __shared__ __align__(16) unsigned short L[128 * 72];  // stride 144B
    const int bid = blockIdx.x;            // b*8 + t
    const int tid = threadIdx.x;
    const float* src = Kg + (size_t)bid * 128 * 768;
    char* outb = (char*)Kws + (size_t)bid * 196608;
    const int kv = tid >> 2;
    const int k0 = (tid & 3) * 16;
    #pragma unroll 1
    for (int st = 0; st < 12; ++st) {
        #pragma unroll
        for (int i = 0; i < 4; ++i) {
            f32x4v v = *(const f32x4v*)(src + (size_t)kv * 768 + st * 64 + k0 + i * 4);
            bf16x4 hb = { (__bf16)v[0], (__bf16)v[1], (__bf16)v[2], (__bf16)v[3] };
            *(bf16x4*)((char*)L + kv * 144 + (k0 + i * 4) * 2) = hb;
        }
        __syncthreads();
        #pragma unroll
        for (int i = 0; i < 2; ++i) {
            int u = tid * 2 + i;                       // [0,1024)
            int ks = u >> 8, ncc = (u >> 6) & 3, l = u & 63;
            bf16x8 f = *(const bf16x8*)((char*)L + (ncc * 32 + (l & 31)) * 144
                                        + ks * 32 + 16 * (l >> 5));
            *(bf16x8*)(outb + (size_t)st * 16384 + u * 16) = f;
        }
        __syncthreads();
    }
}

// ============================ prepass: V (transpose) ============================
__global__ __launch_bounds__(512) void prep_v(const float* __restrict__ Vg,
                                              unsigned short* __restrict__ Vws) {
    __shared__ __align__(16) unsigned short L[128 * 136]; // V^T [d 128][kv], stride 272B
    const int bid = blockIdx.x;            // b*8 + t
    const int tid = threadIdx.x;
    const float* src = Vg + (size_t)bid * 128 * 768;
    char* outb = (char*)Vws + (size_t)bid * 196608;
    const int srg = tid & 31, scg = tid >> 5;
    #pragma unroll 1
    for (int jg = 0; jg < 6; ++jg) {
        #pragma unroll
        for (int i2 = 0; i2 < 2; ++i2) {
            int cg = scg + i2 * 16;
            const float* vp = src + (size_t)(srg * 4) * 768 + jg * 128 + cg * 4;
            f32x4v a0 = *(const f32x4v*)(vp);
            f32x4v a1 = *(const f32x4v*)(vp + 768);
            f32x4v a2 = *(const f32x4v*)(vp + 1536);
            f32x4v a3 = *(const f32x4v*)(vp + 2304);
            #pragma unroll
            for (int c = 0; c < 4; ++c) {
                int d = cg * 4 + c;
                bf16x4 hb = { (__bf16)a0[c], (__bf16)a1[c], (__bf16)a2[c], (__bf16)a3[c] };
                *(bf16x4*)((char*)L + d * 272 + srg * 8) = hb;
            }
        }
        __syncthreads();
        #pragma unroll
        for (int i = 0; i < 4; ++i) {
            int u = tid * 4 + i;                       // [0,2048)
            int kh = u >> 10, ks = (u >> 8) & 3, ncc = (u >> 6) & 3, l = u & 63;
            bf16x8 f = *(const bf16x8*)((char*)L + (ncc * 32 + (l & 31)) * 272
                                        + kh * 128 + ks * 32 + 16 * (l >> 5));
            *(bf16x8*)(outb + (size_t)(jg * 2 + kh) * 16384 + (u & 1023) * 16) = f;
        }
        __syncthreads();
    }
}

// ============================ main kernel ============================
#define OFFK(sl) ((size_t)((sl) >> 2) * 16384 + (size_t)((sl) & 3) * 4096)
#define OFFV(ksl) ((size_t)((ksl) >> 3) * 196608 + (size_t)(((ksl) >> 2) & 1) * 16384 \
                   + (size_t)((ksl) & 3) * 4096)

#define LGKM0_BAR() do {                                            \
    asm volatile("s_waitcnt lgkmcnt(0)" ::: "memory");              \
    __builtin_amdgcn_s_barrier();                                   \
    asm volatile("" ::: "memory"); } while (0)

__global__ __launch_bounds__(512, 2) void lsa_main(
    const unsigned short* __restrict__ Qws, const unsigned short* __restrict__ Kws,
    const unsigned short* __restrict__ Vws, float* __restrict__ Og)
{
    extern __shared__ char sm[];
    const int tid  = threadIdx.x;
    const int lane = tid & 63;
    const int w    = tid >> 6;
    const int hh   = lane >> 5;
    const int l31  = lane & 31;

    int id = blockIdx.x;
    int xcd = id & 7, jj = id >> 3;
    int batch = (jj >> 5) * 16 + xcd * 2 + ((jj >> 4) & 1);
    int qt = jj & 15;

    const char* qimg = (const char*)Qws + (size_t)(batch * 16 + qt) * 98304;
    const char* kimg = (const char*)Kws + (size_t)batch * 1572864;
    const char* vimg = (const char*)Vws + (size_t)batch * 1572864;
    float* redm = (float*)(sm + REDOFF);
    float* redl = (float*)(sm + REDOFF + 2048);

    // ---- stage Q image (96 KB) into LDS ----
    #pragma unroll
    for (int i = 0; i < 12; ++i)
        gld16(qimg + i * 8192 + tid * 16, sm + QOFF + i * 8192 + w * 1024);
    __syncthreads();

    f32x16 acc[3][2];
    #pragma unroll
    for (int g3 = 0; g3 < 3; ++g3)
        #pragma unroll
        for (int qg = 0; qg < 2; ++qg)
            #pragma unroll
            for (int r = 0; r < 16; ++r) acc[g3][qg][r] = 0.0f;
    float m_st[2] = { -3e38f, -3e38f };
    float l_st[2] = { 0.0f, 0.0f };

    const size_t kwoff = (size_t)(w >> 2) * 196608 + (size_t)(w & 3) * 1024
                         + (size_t)lane * 16;
    size_t voff3[3];
    #pragma unroll
    for (int g3 = 0; g3 < 3; ++g3) {
        int dgi = w * 3 + g3;
        voff3[g3] = (size_t)(dgi >> 2) * 32768 + (size_t)(dgi & 3) * 1024
                    + (size_t)lane * 16;
    }
    const int diag_t2 = qt >> 2;

    #pragma unroll 1
    for (int t2 = 0; t2 < 4; ++t2) {
        // ================= QK^T: deep-ring global->reg K, LDS Q =================
        const char* kb = kimg + (size_t)t2 * 393216 + kwoff;
        f32x16 s[2];
        #pragma unroll
        for (int qg = 0; qg < 2; ++qg)
            #pragma unroll
            for (int r = 0; r < 16; ++r) s[qg][r] = 0.0f;

        bf16x8 kr[8];
        #pragma unroll
        for (int j = 0; j < 8; ++j) kr[j] = *(const bf16x8*)(kb + OFFK(j));

        #pragma unroll
        for (int sl = 0; sl < 48; ++sl) {
            bf16x8 kf  = kr[sl & 7];
            bf16x8 qf0 = *(const bf16x8*)(sm + QOFF + (sl * 2 + 0) * 1024 + lane * 16);
            bf16x8 qf1 = *(const bf16x8*)(sm + QOFF + (sl * 2 + 1) * 1024 + lane * 16);
            __builtin_amdgcn_s_setprio(1);
            s[0] = __builtin_amdgcn_mfma_f32_32x32x16_bf16(kf, qf0, s[0], 0, 0, 0);
            s[1] = __builtin_amdgcn_mfma_f32_32x32x16_bf16(kf, qf1, s[1], 0, 0, 0);
            __builtin_amdgcn_s_setprio(0);
            if (sl < 40)
                kr[sl & 7] = *(const bf16x8*)(kb + OFFK(sl + 8));   // WAR-ordered ring refill
        }

        // ---- V ring warm-up: issue now, lands during softmax ----
        const char* vb = vimg + (size_t)t2 * 393216;
        bf16x8 vr[4][3];
        #pragma unroll
        for (int kk = 0; kk < 4; ++kk)
            #pragma unroll
            for (int g3 = 0; g3 < 3; ++g3)
                vr[kk][g3] = *(const bf16x8*)(vb + voff3[g3] + OFFV(kk));

        // diagonal self-exclusion
        if (t2 == diag_t2) {
            #pragma unroll
            for (int qg = 0; qg < 2; ++qg)
                #pragma unroll
                for (int r = 0; r < 16; ++r) {
                    int kvg = t2 * 256 + w * 32 + (r & 3) + 8 * (r >> 2) + 4 * hh;
                    if (kvg == qt * 64 + qg * 32 + l31) s[qg][r] = -3e38f;
                }
        }

        // ================= online softmax (2 q-rows per lane) =================
        #pragma unroll
        for (int qg = 0; qg < 2; ++qg) {
            float pm = s[qg][0];
            #pragma unroll
            for (int r = 1; r < 16; ++r) pm = fmaxf(pm, s[qg][r]);
            pm = fmaxf(pm, __shfl_xor(pm, 32, 64));
            if (hh == 0) redm[(qg * 32 + l31) * 8 + w] = pm;
        }
        LGKM0_BAR();                           // barrier 1 (no vmcnt drain)
        float cf[2];
        #pragma unroll
        for (int qg = 0; qg < 2; ++qg) {
            const float* rp = redm + (qg * 32 + l31) * 8;
            f32x4v a = *(const f32x4v*)rp;
            f32x4v b = *(const f32x4v*)(rp + 4);
            float mn = fmaxf(fmaxf(fmaxf(a[0], a[1]), fmaxf(a[2], a[3])),
                             fmaxf(fmaxf(b[0], b[1]), fmaxf(b[2], b[3])));
            mn = fmaxf(mn, m_st[qg]);
            cf[qg] = __builtin_amdgcn_exp2f(m_st[qg] - mn);
            m_st[qg] = mn;
            float pl = 0.0f;
            #pragma unroll
            for (int r = 0; r < 16; ++r) {
                float e = __builtin_amdgcn_exp2f(s[qg][r] - mn);
                s[qg][r] = e; pl += e;
            }
            pl += __shfl_xor(pl, 32, 64);
            l_st[qg] = l_st[qg] * cf[qg] + pl;
        }
        #pragma unroll
        for (int g3 = 0; g3 < 3; ++g3)
            #pragma unroll
            for (int qg = 0; qg < 2; ++qg)
                #pragma unroll
                for (int r = 0; r < 16; ++r) acc[g3][qg][r] *= cf[qg];

        // P -> fragment layout in LDS
        #pragma unroll
        for (int qg = 0; qg < 2; ++qg)
            #pragma unroll
            for (int g = 0; g < 4; ++g) {
                bf16x4 p4 = { (__bf16)s[qg][4 * g + 0], (__bf16)s[qg][4 * g + 1],
                              (__bf16)s[qg][4 * g + 2], (__bf16)s[qg][4 * g + 3] };
                int blk = (2 * w + (g >> 1)) * 2 + qg;
                int lidx = (g & 1) * 32 + l31;
                *(bf16x4*)(sm + POFF + blk * 1024 + lidx * 16 + hh * 8) = p4;
            }
        LGKM0_BAR();                           // barrier 2 (no vmcnt drain)

        // ================= P @ V: ring-4 global->reg V, LDS P =================
        #pragma unroll
        for (int ksl = 0; ksl < 16; ++ksl) {
            bf16x8 pa0 = *(const bf16x8*)(sm + POFF + (ksl * 2 + 0) * 1024 + lane * 16);
            bf16x8 pa1 = *(const bf16x8*)(sm + POFF + (ksl * 2 + 1) * 1024 + lane * 16);
            __builtin_amdgcn_s_setprio(1);
            #pragma unroll
            for (int g3 = 0; g3 < 3; ++g3) {
                acc[g3][0] = __builtin_amdgcn_mfma_f32_32x32x16_bf16(vr[ksl & 3][g3], pa0, acc[g3][0], 0, 0, 0);
                acc[g3][1] = __builtin_amdgcn_mfma_f32_32x32x16_bf16(vr[ksl & 3][g3], pa1, acc[g3][1], 0, 0, 0);
            }
            __builtin_amdgcn_s_setprio(0);
            if (ksl < 12) {
                #pragma unroll
                for (int g3 = 0; g3 < 3; ++g3)
                    vr[ksl & 3][g3] = *(const bf16x8*)(vb + voff3[g3] + OFFV(ksl + 4));
            }
        }
    }

    // ================= epilogue =================
    #pragma unroll
    for (int qg = 0; qg < 2; ++qg)
        if (hh == 0) redl[(qg * 32 + l31) * 8 + w] = l_st[qg];
    __syncthreads();
    float rinv[2];
    #pragma unroll
    for (int qg = 0; qg < 2; ++qg) {
        const float* rp = redl + (qg * 32 + l31) * 8;
        f32x4v a = *(const f32x4v*)rp;
        f32x4v b = *(const f32x4v*)(rp + 4);
        rinv[qg] = 1.0f / (a[0] + a[1] + a[2] + a[3] + b[0] + b[1] + b[2] + b[3]);
    }

    char* obt = sm + QOFF;                     // reuse Q space: [64 q][256 d] f32, XOR swizzle
    const size_t orow = (size_t)batch * 1024 + (size_t)qt * 64;
    const int q2 = tid >> 3, c8 = tid & 7;

    #pragma unroll
    for (int g3 = 0; g3 < 3; ++g3) {
        __syncthreads();                       // previous pass reads done
        #pragma unroll
        for (int qg = 0; qg < 2; ++qg) {
            int q = qg * 32 + l31;
            int qx = (q & 15) << 4;
            #pragma unroll
            for (int g = 0; g < 4; ++g) {
                f32x4v o4 = { acc[g3][qg][4 * g + 0] * rinv[qg],
                              acc[g3][qg][4 * g + 1] * rinv[qg],
                              acc[g3][qg][4 * g + 2] * rinv[qg],
                              acc[g3][qg][4 * g + 3] * rinv[qg] };
                int dloc = w * 32 + 8 * g + 4 * hh;
                *(f32x4v*)(obt + q * 1024 + ((dloc * 4) ^ qx)) = o4;
            }
        }
        __syncthreads();
        #pragma unroll
        for (int i = 0; i < 8; ++i) {
            int db = c8 * 128 + i * 16;
            f32x4v o = *(const f32x4v*)(obt + q2 * 1024 + (db ^ ((q2 & 15) << 4)));
            int dg = c8 * 96 + g3 * 32 + i * 4;
            *(f32x4v*)(Og + (orow + q2) * 768 + dg) = o;
        }
    }
}

// ============================ fallback (round-2 kernel) ============================
__device__ __forceinline__ void fb_stage_load(f32x4v (&vr)[2][4], const float* __restrict__ Vg,
                                              size_t kvbase, int srg, int scg, int ch) {
    #pragma unroll
    for (int i2 = 0; i2 < 2; ++i2) {
        const float* vp = Vg + kvbase + (size_t)(srg * 4) * 768 + ch * 128 + (scg + i2 * 16) * 4;
        #pragma unroll
        for (int rr = 0; rr < 4; ++rr)
            vr[i2][rr] = *(const f32x4v*)(vp + (size_t)rr * 768);
    }
}
__device__ __forceinline__ void fb_stage_write(const f32x4v (&vr)[2][4], char* Vb, int srg, int scg) {
    #pragma unroll
    for (int i2 = 0; i2 < 2; ++i2) {
        int cg = scg + i2 * 16;
        #pragma unroll
        for (int q4 = 0; q4 < 4; ++q4) {
            int drow = cg * 4 + q4;
            bf16x4 hv = { (__bf16)vr[i2][0][q4], (__bf16)vr[i2][1][q4],
                          (__bf16)vr[i2][2][q4], (__bf16)vr[i2][3][q4] };
            *(bf16x4*)(Vb + drow * 256 + ((srg * 8) ^ ((drow & 15) << 4))) = hv;
        }
    }
}
#define FB_OFF_V  98304
#define FB_OFF_P  131072
#define FB_OFF_RM 147456
#define FB_OFF_RL 148480
#define FB_LDS    149504
__global__ __launch_bounds__(512) void lsa_fb(
    const float* __restrict__ Qg, const float* __restrict__ Kg,
    const float* __restrict__ Vg, const float* __restrict__ Tg,
    float* __restrict__ Og)
{
    extern __shared__ char smem[];
    char*  Qb    = smem;
    char*  Vb    = smem + FB_OFF_V;
    char*  Pb    = smem + FB_OFF_P;
    float* red_m = (float*)(smem + FB_OFF_RM);
    float* red_l = (float*)(smem + FB_OFF_RL);
    const int tid  = threadIdx.x;
    const int lane = tid & 63;
    const int w    = tid >> 6;
    const int mr   = w & 1;
    const int nc   = w >> 1;
    const int half = lane >> 5;
    const int l31  = lane & 31;
    int id = blockIdx.x, xcd = id & 7, jj = id >> 3;
    int batch = (jj >> 5) * 16 + xcd * 2 + ((jj >> 4) & 1);
    int qt = jj & 15;
    const float scale2 = 1.4426950408889634f / Tg[0];
    {
        const float* qp   = Qg + ((size_t)batch * 1024 + (size_t)qt * 64) * 768;
        int   row   = tid >> 3, c0 = tid & 7;
        const float* qrow = qp + (size_t)row * 768;
        char* qdst  = Qb + row * 1536;
        int   rx    = (row & 15) << 4;
        #pragma unroll
        for (int j = 0; j < 24; ++j) {
            int c4 = c0 + j * 8;
            f32x4v q4 = *(const f32x4v*)(qrow + c4 * 4);
            bf16x4 hq = { (__bf16)(q4[0] * scale2), (__bf16)(q4[1] * scale2),
                          (__bf16)(q4[2] * scale2), (__bf16)(q4[3] * scale2) };
            *(bf16x4*)(qdst + ((c4 * 8) ^ rx)) = hq;
        }
    }
    __syncthreads();
    f32x16 acc[6];
    #pragma unroll
    for (int ch = 0; ch < 6; ++ch)
        #pragma unroll
        for (int r = 0; r < 16; ++r) acc[ch][r] = 0.0f;
    float m_st = -3e38f, l_st = 0.0f;
    const int  qrow_g = mr * 32 + l31;
    const int  qglob  = qt * 64 + qrow_g;
    char*      qfbase = Qb + qrow_g * 1536;
    const int  qx     = (qrow_g & 15) << 4;
    char*      pfbase = Pb + qrow_g * 256;
    const int  vrow   = nc * 32 + l31;
    char*      vfbase = Vb + vrow * 256;
    const int  vx     = (vrow & 15) << 4;
    const int  diag_tile = qt >> 1;
    const int  srg = tid & 31, scg = tid >> 5;
    #pragma unroll 1
    for (int t = 0; t < 8; ++t) {
        const size_t kvbase = ((size_t)batch * 1024 + (size_t)t * 128) * 768;
        f32x16 s;
        #pragma unroll
        for (int r = 0; r < 16; ++r) s[r] = 0.0f;
        const float* kptr = Kg + kvbase + (size_t)(nc * 32 + l31) * 768 + 8 * half;
        #pragma unroll
        for (int ch = 0; ch < 6; ++ch) {
            #pragma unroll
            for (int ks = 0; ks < 8; ++ks) {
                f32x4v k0 = *(const f32x4v*)(kptr + ch * 128 + ks * 16);
                f32x4v k1 = *(const f32x4v*)(kptr + ch * 128 + ks * 16 + 4);
                bf16x8 kf = { (__bf16)k0[0], (__bf16)k0[1], (__bf16)k0[2], (__bf16)k0[3],
                              (__bf16)k1[0], (__bf16)k1[1], (__bf16)k1[2], (__bf16)k1[3] };
                bf16x8 qf = *(const bf16x8*)(qfbase + ((ch * 256 + ks * 32 + half * 16) ^ qx));
                s = __builtin_amdgcn_mfma_f32_32x32x16_bf16(kf, qf, s, 0, 0, 0);
            }
        }
        if (t == diag_tile) {
            #pragma unroll
            for (int r = 0; r < 16; ++r) {
                int kvg = t * 128 + nc * 32 + (r & 3) + 8 * (r >> 2) + 4 * half;
                if (kvg == qglob) s[r] = -3e38f;
            }
        }
        f32x4v vr[2][4];
        fb_stage_load(vr, Vg, kvbase, srg, scg, 0);
        float pm = s[0];
        #pragma unroll
        for (int r = 1; r < 16; ++r) pm = fmaxf(pm, s[r]);
        pm = fmaxf(pm, __shfl_xor(pm, 32, 64));
        if (half == 0) red_m[qrow_g * 4 + nc] = pm;
        __syncthreads();
        f32x4v m4 = *(const f32x4v*)(red_m + qrow_g * 4);
        float mnew = fmaxf(fmaxf(m4[0], m4[1]), fmaxf(m4[2], m4[3]));
        mnew = fmaxf(mnew, m_st);
        float cf = __builtin_amdgcn_exp2f(m_st - mnew);
        m_st = mnew;
        float pl = 0.0f;
        #pragma unroll
        for (int r = 0; r < 16; ++r) {
            float e = __builtin_amdgcn_exp2f(s[r] - mnew);
            s[r] = e; pl += e;
        }
        pl += __shfl_xor(pl, 32, 64);
        l_st = l_st * cf + pl;
        #pragma unroll
        for (int ch = 0; ch < 6; ++ch)
            #pragma unroll
            for (int r = 0; r < 16; ++r) acc[ch][r] *= cf;
        #pragma unroll
        for (int g = 0; g < 4; ++g) {
            bf16x4 hp = { (__bf16)s[4*g+0], (__bf16)s[4*g+1],
                          (__bf16)s[4*g+2], (__bf16)s[4*g+3] };
            *(bf16x4*)(pfbase + ((nc * 64 + g * 16 + half * 8) ^ qx)) = hp;
        }
        fb_stage_write(vr, Vb, srg, scg);
        __syncthreads();
        bf16x8 pa[8];
        #pragma unroll
        for (int ks = 0; ks < 8; ++ks)
            pa[ks] = *(const bf16x8*)(pfbase + ((ks * 32 + half * 16) ^ qx));
        #pragma unroll
        for (int ch = 0; ch < 6; ++ch) {
            if (ch < 5) fb_stage_load(vr, Vg, kvbase, srg, scg, ch + 1);
            #pragma unroll
            for (int ks = 0; ks < 8; ++ks) {
                bf16x8 vf = *(const bf16x8*)(vfbase + ((ks * 32 + half * 16) ^ vx));
                acc[ch] = __builtin_amdgcn_mfma_f32_32x32x16_bf16(vf, pa[ks], acc[ch], 0, 0, 0);
            }
            if (ch < 5) {
                __syncthreads();
                fb_stage_write(vr, Vb, srg, scg);
                __syncthreads();
            }
        }
    }
    if (half == 0) red_l[qrow_g * 4 + nc] = l_st;
    __syncthreads();
    f32x4v l4 = *(const f32x4v*)(red_l + qrow_g * 4);
    float rinv = 1.0f / (l4[0] + l4[1] + l4[2] + l4[3]);
    float* op = Og + ((size_t)batch * 1024 + (size_t)qglob) * 768;
    #pragma unroll
    for (int ch = 0; ch < 6; ++ch)
        #pragma unroll
        for (int g = 0; g < 4; ++g) {
            f32x4v o4 = { acc[ch][4*g+0] * rinv, acc[ch][4*g+1] * rinv,
                          acc[ch][4*g+2] * rinv, acc[ch][4*g+3] * rinv };
            *(f32x4v*)(op + ch * 128 + nc * 32 + g * 8 + half * 4) = o4;
        }
}

extern "C" void kernel_launch(void* const* d_in, const int* in_sizes, int n_in,
                              void* d_out, int out_size, void* d_ws, size_t ws_size,
                              hipStream_t stream) {
    (void)in_sizes; (void)n_in; (void)out_size;
    const float* Q = (const float*)d_in[0];
    const float* K = (const float*)d_in[1];
    const float* V = (const float*)d_in[2];
    const float* T = (const float*)d_in[3];
    float* O = (float*)d_out;
    if (ws_size >= WS_NEEDED) {
        unsigned short* Qws = (unsigned short*)((char*)d_ws + WS_Q);
        unsigned short* Kws = (unsigned short*)((char*)d_ws + WS_K);
        unsigned short* Vws = (unsigned short*)((char*)d_ws + WS_V);
        prep_q<<<dim3(1024), dim3(256), 0, stream>>>(Q, T, Qws);
        prep_k<<<dim3(512),  dim3(512), 0, stream>>>(K, Kws);
        prep_v<<<dim3(512),  dim3(512), 0, stream>>>(V, Vws);
        lsa_main<<<dim3(1024), dim3(512), LDS_MAIN, stream>>>(Qws, Kws, Vws, O);
    } else {
        lsa_fb<<<dim3(1024), dim3(512), FB_LDS, stream>>>(Q, K, V, T, O);
    }
}